// Round 7
// baseline (199.786 us; speedup 1.0000x reference)
//
#include <hip/hip_runtime.h>
#include <hip/hip_bf16.h>

// Sizes fixed by the problem.
#define BS    64
#define KDIM  256   // in_dim
#define ICAP  256   // I = 16*16
#define JCAP  64    // J out-caps
#define D2    32
#define OUTD  2048  // J*D2
#define NPART 16    // partial rows per b from route passes (1 per block)

typedef short bf16x8 __attribute__((ext_vector_type(8)));
typedef float f32x4  __attribute__((ext_vector_type(4)));

static __device__ __forceinline__ float bf2f(unsigned u16) {
  union { unsigned u; float f; } v; v.u = u16 << 16; return v.f;
}
static __device__ __forceinline__ unsigned short f2bf(float x) {
  union { float f; unsigned u; } v; v.f = x;
  unsigned r = v.u + 0x7fffu + ((v.u >> 16) & 1u);
  return (unsigned short)(r >> 16);
}
static __device__ __forceinline__ void unpack8(uint4 u, float* f) {
  f[0] = bf2f(u.x & 0xffffu); f[1] = bf2f(u.x >> 16);
  f[2] = bf2f(u.y & 0xffffu); f[3] = bf2f(u.y >> 16);
  f[4] = bf2f(u.z & 0xffffu); f[5] = bf2f(u.z >> 16);
  f[6] = bf2f(u.w & 0xffffu); f[7] = bf2f(u.w >> 16);
}
// async global->LDS, 16B per lane; LDS dest = wave-uniform base + lane*16
static __device__ __forceinline__ void gl_lds16(const unsigned short* g,
                                                unsigned short* l) {
  __builtin_amdgcn_global_load_lds(
      (const __attribute__((address_space(1))) unsigned int*)g,
      (__attribute__((address_space(3))) unsigned int*)l, 16, 0, 0);
}

// ---------------------------------------------------------------------------
// prep: grid-partitioned fusion of
//   [0,256)      conv_w      : W f32 -> Wbf bf16
//   [256,1280)   transpose_x : x f32 [b][k][i] -> xT bf16 [b][i][k]
//   [1280,1536)  softmax_c0  : c0[b][i][j] = softmax_j(b_init[b][j][i]) bf16
// ---------------------------------------------------------------------------
__global__ __launch_bounds__(256) void prep(
    const float* __restrict__ W, const float* __restrict__ x,
    const float* __restrict__ Binit,
    unsigned short* __restrict__ Wbf, unsigned short* __restrict__ xT,
    unsigned short* __restrict__ c0)
{
  __shared__ union {
    float Ls[64][65];   // transpose tile
    float Bs[64][68];   // softmax tile [j][ii]
  } sm;
  const int t   = threadIdx.x;
  const int blk = blockIdx.x;

  if (blk < 256) {
    // ---- conv_w ----
    const int g = blk * 256 + t;
    const float* s = W + (size_t)g * 8;
    f32x4 a = *(const f32x4*)s;
    f32x4 b = *(const f32x4*)(s + 4);
    uint4 o;
    o.x = (unsigned)f2bf(a.x) | ((unsigned)f2bf(a.y) << 16);
    o.y = (unsigned)f2bf(a.z) | ((unsigned)f2bf(a.w) << 16);
    o.z = (unsigned)f2bf(b.x) | ((unsigned)f2bf(b.y) << 16);
    o.w = (unsigned)f2bf(b.z) | ((unsigned)f2bf(b.w) << 16);
    *(uint4*)(Wbf + (size_t)g * 8) = o;
  } else if (blk < 1280) {
    // ---- transpose_x ----
    const int bid = blk - 256;
    const int i0  = (bid & 3) * 64;
    const int k0  = ((bid >> 2) & 3) * 64;
    const int b   = bid >> 4;
    for (int it = 0; it < 4; ++it) {
      const int k  = it * 16 + (t >> 4);
      const int i4 = (t & 15) * 4;
      f32x4 v = *(const f32x4*)(x + ((size_t)(b * KDIM + k0 + k) * ICAP) + i0 + i4);
      sm.Ls[k][i4 + 0] = v.x; sm.Ls[k][i4 + 1] = v.y;
      sm.Ls[k][i4 + 2] = v.z; sm.Ls[k][i4 + 3] = v.w;
    }
    __syncthreads();
    const int i  = t >> 2;
    const int kc = (t & 3) * 16;
    unsigned pk[8];
    for (int q = 0; q < 8; ++q) {
      float lo = sm.Ls[kc + 2 * q][i];
      float hi = sm.Ls[kc + 2 * q + 1][i];
      pk[q] = (unsigned)f2bf(lo) | ((unsigned)f2bf(hi) << 16);
    }
    unsigned short* dst = xT + ((size_t)(b * ICAP + i0 + i) * KDIM) + k0 + kc;
    uint4 s0; s0.x = pk[0]; s0.y = pk[1]; s0.z = pk[2]; s0.w = pk[3];
    uint4 s1; s1.x = pk[4]; s1.y = pk[5]; s1.z = pk[6]; s1.w = pk[7];
    *(uint4*)dst       = s0;
    *(uint4*)(dst + 8) = s1;
  } else {
    // ---- softmax_c0, 64x64 tile: block = (b, i-quarter) ----
    const int bid = blk - 1280;
    const int b   = bid >> 2;
    const int q   = bid & 3;
    {
      const int j  = t >> 2;
      const int c4 = (t & 3) * 16;
      const float* src = Binit + ((size_t)(b * JCAP + j) * ICAP) + q * 64 + c4;
      for (int r = 0; r < 4; ++r) {
        f32x4 v = *(const f32x4*)(src + r * 4);
        *(f32x4*)&sm.Bs[j][c4 + r * 4] = v;
      }
    }
    __syncthreads();
    if (t < 64) {
      const int ii = t;
      float m = -3.0e38f;
      for (int j = 0; j < 64; ++j) m = fmaxf(m, sm.Bs[j][ii]);
      float se = 0.f;
      for (int j = 0; j < 64; ++j) se += __expf(sm.Bs[j][ii] - m);
      const float inv = 1.0f / se;
      unsigned short* dst = c0 + ((size_t)(b * ICAP + q * 64 + ii) * JCAP);
      for (int qq = 0; qq < 8; ++qq) {
        unsigned pk[4];
        for (int h = 0; h < 4; ++h) {
          float lo = __expf(sm.Bs[qq * 8 + 2 * h][ii] - m) * inv;
          float hi = __expf(sm.Bs[qq * 8 + 2 * h + 1][ii] - m) * inv;
          pk[h] = (unsigned)f2bf(lo) | ((unsigned)f2bf(hi) << 16);
        }
        uint4 s; s.x = pk[0]; s.y = pk[1]; s.z = pk[2]; s.w = pk[3];
        *(uint4*)(dst + qq * 8) = s;
      }
    }
  }
}

// ---------------------------------------------------------------------------
// gemm_pred: P[b][i][o] = sum_k W[o][k]*x[b][k][i] + Wb[o]  (bf16 out)
// + fused routing-pass-0 s-accumulation into s0part (8 rows/b) using c0.
// LDS 32 KB (split epilogue halves) -> 5 blocks/CU.
// ---------------------------------------------------------------------------
__global__ __launch_bounds__(256) void gemm_pred(
    const unsigned short* __restrict__ Wbf,  // [OUTD][KDIM] bf16
    const unsigned short* __restrict__ xT,   // [BS][ICAP][KDIM] bf16
    const float* __restrict__ Wb,            // [OUTD] f32
    const unsigned short* __restrict__ c0,   // [BS][ICAP][JCAP] bf16
    unsigned short* __restrict__ P,          // [BS][ICAP][OUTD] bf16
    float* __restrict__ s0part)              // [BS][8][OUTD] f32
{
  __shared__ union {
    unsigned short AB[2][128][64];           // swizzled, unpadded (32 KiB)
    struct {
      unsigned short C[64][136];             // half-tile [i][o] (272B stride)
      unsigned short c0t[128][4];            // c0 tile for this block's 4 j
    } ep;
  } sm;

  const int tid = threadIdx.x;
  const int b   = blockIdx.z;
  const int o0  = blockIdx.x * 128;
  const int i0  = blockIdx.y * 128;
  const int l   = tid & 63;
  const int m   = l & 15;
  const int w   = tid >> 6;
  const int wo  = (w & 1) * 64;

  const int srow = l >> 3;
  const int gch  = (l & 7) ^ srow;

  f32x4 acc[4][4];
  for (int a = 0; a < 4; ++a)
    for (int c = 0; c < 4; ++c) acc[a][c] = (f32x4){0.f, 0.f, 0.f, 0.f};

  for (int r = 0; r < 4; ++r) {
    const int k0 = r * 64;
    __syncthreads();
    for (int c = 0; c < 4; ++c) {
      const int q   = w * 4 + c;
      const int row = q * 8 + srow;
      gl_lds16(Wbf + (size_t)(o0 + row) * KDIM + k0 + gch * 8,
               &sm.AB[0][q * 8][0]);
      gl_lds16(xT + ((size_t)(b * ICAP + i0 + row) * KDIM) + k0 + gch * 8,
               &sm.AB[1][q * 8][0]);
    }
    __syncthreads();
    for (int ks = 0; ks < 2; ++ks) {
      const int clog = ks * 4 + (l >> 4);
      bf16x8 af[4], bfg[4];
      for (int ti = 0; ti < 4; ++ti) {
        const int row = wo + 16 * ti + m;
        af[ti] = *(const bf16x8*)&sm.AB[0][row][(clog ^ (m & 7)) * 8];
      }
      for (int tj = 0; tj < 4; ++tj) {
        const int row = (w >> 1) * 64 + 16 * tj + m;
        bfg[tj] = *(const bf16x8*)&sm.AB[1][row][(clog ^ (m & 7)) * 8];
      }
      for (int ti = 0; ti < 4; ++ti)
        for (int tj = 0; tj < 4; ++tj)
          acc[ti][tj] = __builtin_amdgcn_mfma_f32_16x16x32_bf16(
              af[ti], bfg[tj], acc[ti][tj], 0, 0, 0);
    }
  }

  __syncthreads();   // MFMA done; AB region reusable
  if (tid < 128) {
    const int j0 = blockIdx.x * 4;
    uint2 v = *(const uint2*)(c0 + ((size_t)(b * ICAP + i0 + tid) * JCAP) + j0);
    *(uint2*)&sm.ep.c0t[tid][0] = v;
  }

  for (int half = 0; half < 2; ++half) {
    __syncthreads();
    if ((w >> 1) == half) {
      // D layout: row(M=o) = (l>>4)*4 + reg, col(N=i) = l&15 -> C[i][o]
      const int q4 = (l >> 4) * 4;
      for (int ti = 0; ti < 4; ++ti) {
        const int ob = wo + 16 * ti + q4;
        f32x4 wb4 = *(const f32x4*)(Wb + o0 + ob);
        for (int tj = 0; tj < 4; ++tj) {
          const int ii = 16 * tj + m;    // i within this half
          f32x4 a = acc[ti][tj];
          uint2 pk;
          pk.x = (unsigned)f2bf(a.x + wb4.x) | ((unsigned)f2bf(a.y + wb4.y) << 16);
          pk.y = (unsigned)f2bf(a.z + wb4.z) | ((unsigned)f2bf(a.w + wb4.w) << 16);
          *(uint2*)&sm.ep.C[ii][ob] = pk;
        }
      }
    }
    __syncthreads();
    // coalesced write-out: 64 rows x 256B
    for (int rr = 0; rr < 4; ++rr) {
      const int id  = rr * 256 + tid;
      const int row = id >> 4;
      const int seg = id & 15;
      uint4 v = *(const uint4*)&sm.ep.C[row][seg * 8];
      *(uint4*)(P + ((size_t)(b * ICAP + i0 + half * 64 + row) * OUTD) + o0 + seg * 8) = v;
    }
    // fused pass-0 partial: s0part row p = y*4 + half*2 + q
    {
      const int oc = tid & 127;
      const int q  = tid >> 7;
      const int jj = oc >> 5;
      float s = 0.f;
      for (int r2 = 0; r2 < 32; ++r2) {
        const int il = q * 32 + r2;
        s += bf2f(sm.ep.C[il][oc]) * bf2f(sm.ep.c0t[half * 64 + il][jj]);
      }
      const int p = blockIdx.y * 4 + half * 2 + q;
      s0part[((size_t)(b * 8 + p) * OUTD) + o0 + oc] = s;
    }
  }
}

// ---------------------------------------------------------------------------
// squash_v: reduce npart partial rows, squash, write f32 [b][o] (V or output).
// One block per b; thread covers 8 o's (one j per 4-lane group).
// ---------------------------------------------------------------------------
__global__ __launch_bounds__(256) void squash_v(
    const float* __restrict__ part,      // [BS][npart][OUTD] f32
    const int npart,
    float* __restrict__ dst)             // [BS][OUTD] f32 (j-major)
{
  const int tid = threadIdx.x;
  const int b   = blockIdx.x;
  const float* base = part + (size_t)b * npart * OUTD + tid * 8;
  float s[8] = {0.f,0.f,0.f,0.f,0.f,0.f,0.f,0.f};
  for (int p = 0; p < npart; ++p) {
    f32x4 a = *(const f32x4*)(base + (size_t)p * OUTD);
    f32x4 c = *(const f32x4*)(base + (size_t)p * OUTD + 4);
    s[0] += a.x; s[1] += a.y; s[2] += a.z; s[3] += a.w;
    s[4] += c.x; s[5] += c.y; s[6] += c.z; s[7] += c.w;
  }
  float sq = 0.f;
  for (int c = 0; c < 8; ++c) sq += s[c] * s[c];
  sq += __shfl_xor(sq, 1, 64);
  sq += __shfl_xor(sq, 2, 64);          // norm over the 4-lane j-group
  float scale = (sq / (1.0f + sq)) / sqrtf(sq + 1e-8f);
  float* d = dst + (size_t)b * OUTD + tid * 8;
  f32x4 t0 = {scale*s[0], scale*s[1], scale*s[2], scale*s[3]};
  f32x4 t1 = {scale*s[4], scale*s[5], scale*s[6], scale*s[7]};
  *(f32x4*)d       = t0;
  *(f32x4*)(d + 4) = t1;
}

// ---------------------------------------------------------------------------
// route_fused: route phase with precomputed V + block-level s reduction.
// Grid 1024 = (b, g); block g covers i in [g*16, g*16+16), wave w -> 4 i's.
// ---------------------------------------------------------------------------
__global__ __launch_bounds__(256, 4) void route_fused(
    const unsigned short* __restrict__ P,     // [BS][ICAP][OUTD] bf16
    const float* __restrict__ Binit,          // [BS][JCAP][ICAP] f32
    float* __restrict__ B1,                   // [BS][ICAP][JCAP] f32
    const float* __restrict__ Vin,            // [BS][OUTD] f32 (j-major)
    float* __restrict__ part_out,             // [BS][NPART][OUTD] f32
    const int pass)
{
  __shared__ float Ps[4][2112];    // per-wave s partials [j*33+d]

  const int tid = threadIdx.x;
  const int l   = tid & 63;              // j
  const int w   = tid >> 6;
  const int b   = blockIdx.x >> 4;
  const int g   = blockIdx.x & 15;

  float vv[32];
  {
    const float* vp = Vin + (size_t)b * OUTD + l * D2;
    for (int q = 0; q < 8; ++q) {
      f32x4 t = *(const f32x4*)(vp + q * 4);
      vv[q*4+0] = t.x; vv[q*4+1] = t.y; vv[q*4+2] = t.z; vv[q*4+3] = t.w;
    }
  }

  const int i0 = g * 16 + w * 4;
  float bold[4];
  if (pass == 1) {
    f32x4 t = *(const f32x4*)(Binit + (size_t)(b * JCAP + l) * ICAP + i0);
    bold[0] = t.x; bold[1] = t.y; bold[2] = t.z; bold[3] = t.w;
  } else {
    for (int ii = 0; ii < 4; ++ii)
      bold[ii] = B1[((size_t)(b * ICAP + i0 + ii)) * JCAP + l];
  }

  float sacc[32];
  for (int k = 0; k < 32; ++k) sacc[k] = 0.f;

  const unsigned short* pbase = P + ((size_t)(b * ICAP + i0) * OUTD) + l * D2;

#pragma unroll
  for (int ii = 0; ii < 4; ++ii) {
    uint4 u0 = *(const uint4*)(pbase + (size_t)ii * OUTD);
    uint4 u1 = *(const uint4*)(pbase + (size_t)ii * OUTD + 8);
    uint4 u2 = *(const uint4*)(pbase + (size_t)ii * OUTD + 16);
    uint4 u3 = *(const uint4*)(pbase + (size_t)ii * OUTD + 24);
    float ps[32];
    unpack8(u0, ps); unpack8(u1, ps + 8); unpack8(u2, ps + 16); unpack8(u3, ps + 24);

    float db = 0.f;
    for (int k = 0; k < 32; ++k) db += ps[k] * vv[k];
    float bnew = bold[ii] + db;
    if (pass == 1) B1[((size_t)(b * ICAP + i0 + ii)) * JCAP + l] = bnew;

    // softmax over 64 lanes (= J)
    float mx = bnew;
    for (int off = 1; off < 64; off <<= 1) mx = fmaxf(mx, __shfl_xor(mx, off, 64));
    float e = __expf(bnew - mx);
    float se = e;
    for (int off = 1; off < 64; off <<= 1) se += __shfl_xor(se, off, 64);
    float c = e / se;
    for (int k = 0; k < 32; ++k) sacc[k] += c * ps[k];
  }

  for (int k = 0; k < 32; ++k) Ps[w][l * 33 + k] = sacc[k];
  __syncthreads();

  // block reduce 4 waves -> part_out[b][g]
  {
    const int o0 = tid * 8;
    float s[8];
    for (int c = 0; c < 8; ++c) {
      const int o = o0 + c, j = o >> 5, d = o & 31, idx = j * 33 + d;
      s[c] = Ps[0][idx] + Ps[1][idx] + Ps[2][idx] + Ps[3][idx];
    }
    float* dst = part_out + ((size_t)(b * NPART + g)) * OUTD + o0;
    f32x4 t0 = {s[0], s[1], s[2], s[3]};
    f32x4 t1 = {s[4], s[5], s[6], s[7]};
    *(f32x4*)dst       = t0;
    *(f32x4*)(dst + 4) = t1;
  }
}

// ---------------------------------------------------------------------------
extern "C" void kernel_launch(void* const* d_in, const int* in_sizes, int n_in,
                              void* d_out, int out_size, void* d_ws, size_t ws_size,
                              hipStream_t stream) {
  const float* x  = (const float*)d_in[0];
  const float* bi = (const float*)d_in[1];
  const float* W  = (const float*)d_in[2];
  const float* Wb = (const float*)d_in[3];
  float* out = (float*)d_out;

  char* ws = (char*)d_ws;
  const size_t MiB = 1024 * 1024;
  unsigned short* P        = (unsigned short*)ws;               // [0,64) MiB
  // overlays (lifetimes):
  //   xT [64,72): prep->gemm.  partial1 [64,72): route1->squash_v (after xT dead)
  //   s0part [72,76), Wbf [76,77), c0 [77,79): prep/gemm era
  //   partial2 [72,80): route2->squash_v (after s0part/Wbf/c0 dead)
  unsigned short* xT       = (unsigned short*)(ws + 64 * MiB);
  float*          partial1 = (float*)(ws + 64 * MiB);
  float*          s0part   = (float*)(ws + 72 * MiB);
  unsigned short* Wbf      = (unsigned short*)(ws + 76 * MiB);
  unsigned short* c0       = (unsigned short*)(ws + 77 * MiB);
  float*          partial2 = (float*)(ws + 72 * MiB);
  float* B1                = (float*)(ws + 80 * MiB);           // [80,84)
  float* V1                = (float*)(ws + 84 * MiB);           // 0.5 MiB
  float* V2                = (float*)(ws + 84 * MiB + 512 * 1024);

  prep<<<dim3(1536), 256, 0, stream>>>(W, x, bi, Wbf, xT, c0);
  gemm_pred<<<dim3(16, 2, 64), 256, 0, stream>>>(Wbf, xT, Wb, c0, P, s0part);
  squash_v<<<dim3(64), 256, 0, stream>>>(s0part, 8, V1);
  route_fused<<<dim3(1024), 256, 0, stream>>>(P, bi, B1, V1, partial1, 1);
  squash_v<<<dim3(64), 256, 0, stream>>>(partial1, NPART, V2);
  route_fused<<<dim3(1024), 256, 0, stream>>>(P, bi, B1, V2, partial2, 2);
  squash_v<<<dim3(64), 256, 0, stream>>>(partial2, NPART, out);
}

// Round 8
// 162.635 us; speedup vs baseline: 1.2284x; 1.2284x over previous
//
#include <hip/hip_runtime.h>
#include <hip/hip_bf16.h>

// Sizes fixed by the problem.
#define BS    64
#define KDIM  256   // in_dim
#define ICAP  256   // I = 16*16
#define JCAP  64    // J out-caps
#define D2    32
#define OUTD  2048  // J*D2
#define NPART 16    // partial rows per b from route passes (1 per block)

typedef short bf16x8 __attribute__((ext_vector_type(8)));
typedef float f32x4  __attribute__((ext_vector_type(4)));

static __device__ __forceinline__ float bf2f(unsigned u16) {
  union { unsigned u; float f; } v; v.u = u16 << 16; return v.f;
}
static __device__ __forceinline__ unsigned short f2bf(float x) {
  union { float f; unsigned u; } v; v.f = x;
  unsigned r = v.u + 0x7fffu + ((v.u >> 16) & 1u);
  return (unsigned short)(r >> 16);
}
static __device__ __forceinline__ void unpack8(uint4 u, float* f) {
  f[0] = bf2f(u.x & 0xffffu); f[1] = bf2f(u.x >> 16);
  f[2] = bf2f(u.y & 0xffffu); f[3] = bf2f(u.y >> 16);
  f[4] = bf2f(u.z & 0xffffu); f[5] = bf2f(u.z >> 16);
  f[6] = bf2f(u.w & 0xffffu); f[7] = bf2f(u.w >> 16);
}
// async global->LDS, 16B per lane; LDS dest = wave-uniform base + lane*16
static __device__ __forceinline__ void gl_lds16(const unsigned short* g,
                                                unsigned short* l) {
  __builtin_amdgcn_global_load_lds(
      (const __attribute__((address_space(1))) unsigned int*)g,
      (__attribute__((address_space(3))) unsigned int*)l, 16, 0, 0);
}

// ---------------------------------------------------------------------------
// prep: grid-partitioned fusion of
//   [0,256)      conv_w      : W f32 -> Wbf bf16
//   [256,1280)   transpose_x : x f32 [b][k][i] -> xT bf16 [b][i][k]
//   [1280,1536)  softmax_c0  : c0[b][i][j] = softmax_j(b_init[b][j][i]) bf16
// ---------------------------------------------------------------------------
__global__ __launch_bounds__(256) void prep(
    const float* __restrict__ W, const float* __restrict__ x,
    const float* __restrict__ Binit,
    unsigned short* __restrict__ Wbf, unsigned short* __restrict__ xT,
    unsigned short* __restrict__ c0)
{
  __shared__ union {
    float Ls[64][65];   // transpose tile
    float Bs[64][68];   // softmax tile [j][ii]
  } sm;
  const int t   = threadIdx.x;
  const int blk = blockIdx.x;

  if (blk < 256) {
    // ---- conv_w ----
    const int g = blk * 256 + t;
    const float* s = W + (size_t)g * 8;
    f32x4 a = *(const f32x4*)s;
    f32x4 b = *(const f32x4*)(s + 4);
    uint4 o;
    o.x = (unsigned)f2bf(a.x) | ((unsigned)f2bf(a.y) << 16);
    o.y = (unsigned)f2bf(a.z) | ((unsigned)f2bf(a.w) << 16);
    o.z = (unsigned)f2bf(b.x) | ((unsigned)f2bf(b.y) << 16);
    o.w = (unsigned)f2bf(b.z) | ((unsigned)f2bf(b.w) << 16);
    *(uint4*)(Wbf + (size_t)g * 8) = o;
  } else if (blk < 1280) {
    // ---- transpose_x ----
    const int bid = blk - 256;
    const int i0  = (bid & 3) * 64;
    const int k0  = ((bid >> 2) & 3) * 64;
    const int b   = bid >> 4;
    for (int it = 0; it < 4; ++it) {
      const int k  = it * 16 + (t >> 4);
      const int i4 = (t & 15) * 4;
      f32x4 v = *(const f32x4*)(x + ((size_t)(b * KDIM + k0 + k) * ICAP) + i0 + i4);
      sm.Ls[k][i4 + 0] = v.x; sm.Ls[k][i4 + 1] = v.y;
      sm.Ls[k][i4 + 2] = v.z; sm.Ls[k][i4 + 3] = v.w;
    }
    __syncthreads();
    const int i  = t >> 2;
    const int kc = (t & 3) * 16;
    unsigned pk[8];
    for (int q = 0; q < 8; ++q) {
      float lo = sm.Ls[kc + 2 * q][i];
      float hi = sm.Ls[kc + 2 * q + 1][i];
      pk[q] = (unsigned)f2bf(lo) | ((unsigned)f2bf(hi) << 16);
    }
    unsigned short* dst = xT + ((size_t)(b * ICAP + i0 + i) * KDIM) + k0 + kc;
    uint4 s0; s0.x = pk[0]; s0.y = pk[1]; s0.z = pk[2]; s0.w = pk[3];
    uint4 s1; s1.x = pk[4]; s1.y = pk[5]; s1.z = pk[6]; s1.w = pk[7];
    *(uint4*)dst       = s0;
    *(uint4*)(dst + 8) = s1;
  } else {
    // ---- softmax_c0, 64x64 tile: block = (b, i-quarter) ----
    const int bid = blk - 1280;
    const int b   = bid >> 2;
    const int q   = bid & 3;
    {
      const int j  = t >> 2;
      const int c4 = (t & 3) * 16;
      const float* src = Binit + ((size_t)(b * JCAP + j) * ICAP) + q * 64 + c4;
      for (int r = 0; r < 4; ++r) {
        f32x4 v = *(const f32x4*)(src + r * 4);
        *(f32x4*)&sm.Bs[j][c4 + r * 4] = v;
      }
    }
    __syncthreads();
    if (t < 64) {
      const int ii = t;
      float m = -3.0e38f;
      for (int j = 0; j < 64; ++j) m = fmaxf(m, sm.Bs[j][ii]);
      float se = 0.f;
      for (int j = 0; j < 64; ++j) se += __expf(sm.Bs[j][ii] - m);
      const float inv = 1.0f / se;
      unsigned short* dst = c0 + ((size_t)(b * ICAP + q * 64 + ii) * JCAP);
      for (int qq = 0; qq < 8; ++qq) {
        unsigned pk[4];
        for (int h = 0; h < 4; ++h) {
          float lo = __expf(sm.Bs[qq * 8 + 2 * h][ii] - m) * inv;
          float hi = __expf(sm.Bs[qq * 8 + 2 * h + 1][ii] - m) * inv;
          pk[h] = (unsigned)f2bf(lo) | ((unsigned)f2bf(hi) << 16);
        }
        uint4 s; s.x = pk[0]; s.y = pk[1]; s.z = pk[2]; s.w = pk[3];
        *(uint4*)(dst + qq * 8) = s;
      }
    }
  }
}

// ---------------------------------------------------------------------------
// gemm_pred: P[b][i][o] = sum_k W[o][k]*x[b][k][i] + Wb[o]  (bf16 out)
// + fused routing-pass-0 s-accumulation into s0part (8 rows/b) using c0.
// ---------------------------------------------------------------------------
__global__ __launch_bounds__(256) void gemm_pred(
    const unsigned short* __restrict__ Wbf,  // [OUTD][KDIM] bf16
    const unsigned short* __restrict__ xT,   // [BS][ICAP][KDIM] bf16
    const float* __restrict__ Wb,            // [OUTD] f32
    const unsigned short* __restrict__ c0,   // [BS][ICAP][JCAP] bf16
    unsigned short* __restrict__ P,          // [BS][ICAP][OUTD] bf16
    float* __restrict__ s0part)              // [BS][8][OUTD] f32
{
  __shared__ union {
    unsigned short AB[2][128][64];           // swizzled, unpadded (32 KiB)
    struct {
      unsigned short C[64][136];             // half-tile [i][o] (272B stride)
      unsigned short c0t[128][4];            // c0 tile for this block's 4 j
    } ep;
  } sm;

  const int tid = threadIdx.x;
  const int b   = blockIdx.z;
  const int o0  = blockIdx.x * 128;
  const int i0  = blockIdx.y * 128;
  const int l   = tid & 63;
  const int m   = l & 15;
  const int w   = tid >> 6;
  const int wo  = (w & 1) * 64;

  const int srow = l >> 3;
  const int gch  = (l & 7) ^ srow;

  f32x4 acc[4][4];
  for (int a = 0; a < 4; ++a)
    for (int c = 0; c < 4; ++c) acc[a][c] = (f32x4){0.f, 0.f, 0.f, 0.f};

  for (int r = 0; r < 4; ++r) {
    const int k0 = r * 64;
    __syncthreads();
    for (int c = 0; c < 4; ++c) {
      const int q   = w * 4 + c;
      const int row = q * 8 + srow;
      gl_lds16(Wbf + (size_t)(o0 + row) * KDIM + k0 + gch * 8,
               &sm.AB[0][q * 8][0]);
      gl_lds16(xT + ((size_t)(b * ICAP + i0 + row) * KDIM) + k0 + gch * 8,
               &sm.AB[1][q * 8][0]);
    }
    __syncthreads();
    for (int ks = 0; ks < 2; ++ks) {
      const int clog = ks * 4 + (l >> 4);
      bf16x8 af[4], bfg[4];
      for (int ti = 0; ti < 4; ++ti) {
        const int row = wo + 16 * ti + m;
        af[ti] = *(const bf16x8*)&sm.AB[0][row][(clog ^ (m & 7)) * 8];
      }
      for (int tj = 0; tj < 4; ++tj) {
        const int row = (w >> 1) * 64 + 16 * tj + m;
        bfg[tj] = *(const bf16x8*)&sm.AB[1][row][(clog ^ (m & 7)) * 8];
      }
      for (int ti = 0; ti < 4; ++ti)
        for (int tj = 0; tj < 4; ++tj)
          acc[ti][tj] = __builtin_amdgcn_mfma_f32_16x16x32_bf16(
              af[ti], bfg[tj], acc[ti][tj], 0, 0, 0);
    }
  }

  __syncthreads();   // MFMA done; AB region reusable
  if (tid < 128) {
    const int j0 = blockIdx.x * 4;
    uint2 v = *(const uint2*)(c0 + ((size_t)(b * ICAP + i0 + tid) * JCAP) + j0);
    *(uint2*)&sm.ep.c0t[tid][0] = v;
  }

  for (int half = 0; half < 2; ++half) {
    __syncthreads();
    if ((w >> 1) == half) {
      // D layout: row(M=o) = (l>>4)*4 + reg, col(N=i) = l&15 -> C[i][o]
      const int q4 = (l >> 4) * 4;
      for (int ti = 0; ti < 4; ++ti) {
        const int ob = wo + 16 * ti + q4;
        f32x4 wb4 = *(const f32x4*)(Wb + o0 + ob);
        for (int tj = 0; tj < 4; ++tj) {
          const int ii = 16 * tj + m;    // i within this half
          f32x4 a = acc[ti][tj];
          uint2 pk;
          pk.x = (unsigned)f2bf(a.x + wb4.x) | ((unsigned)f2bf(a.y + wb4.y) << 16);
          pk.y = (unsigned)f2bf(a.z + wb4.z) | ((unsigned)f2bf(a.w + wb4.w) << 16);
          *(uint2*)&sm.ep.C[ii][ob] = pk;
        }
      }
    }
    __syncthreads();
    // coalesced write-out: 64 rows x 256B
    for (int rr = 0; rr < 4; ++rr) {
      const int id  = rr * 256 + tid;
      const int row = id >> 4;
      const int seg = id & 15;
      uint4 v = *(const uint4*)&sm.ep.C[row][seg * 8];
      *(uint4*)(P + ((size_t)(b * ICAP + i0 + half * 64 + row) * OUTD) + o0 + seg * 8) = v;
    }
    // fused pass-0 partial: s0part row p = y*4 + half*2 + q
    {
      const int oc = tid & 127;
      const int q  = tid >> 7;
      const int jj = oc >> 5;
      float s = 0.f;
      for (int r2 = 0; r2 < 32; ++r2) {
        const int il = q * 32 + r2;
        s += bf2f(sm.ep.C[il][oc]) * bf2f(sm.ep.c0t[half * 64 + il][jj]);
      }
      const int p = blockIdx.y * 4 + half * 2 + q;
      s0part[((size_t)(b * 8 + p) * OUTD) + o0 + oc] = s;
    }
  }
}

// ---------------------------------------------------------------------------
// squash_v: reduce npart partial rows, squash, write f32 [b][o] (V or output).
// One block per b; thread covers 8 o's (one j per 4-lane group).
// ---------------------------------------------------------------------------
__global__ __launch_bounds__(256) void squash_v(
    const float* __restrict__ part,      // [BS][npart][OUTD] f32
    const int npart,
    float* __restrict__ dst)             // [BS][OUTD] f32 (j-major)
{
  const int tid = threadIdx.x;
  const int b   = blockIdx.x;
  const float* base = part + (size_t)b * npart * OUTD + tid * 8;
  float s[8] = {0.f,0.f,0.f,0.f,0.f,0.f,0.f,0.f};
  for (int p = 0; p < npart; ++p) {
    f32x4 a = *(const f32x4*)(base + (size_t)p * OUTD);
    f32x4 c = *(const f32x4*)(base + (size_t)p * OUTD + 4);
    s[0] += a.x; s[1] += a.y; s[2] += a.z; s[3] += a.w;
    s[4] += c.x; s[5] += c.y; s[6] += c.z; s[7] += c.w;
  }
  float sq = 0.f;
  for (int c = 0; c < 8; ++c) sq += s[c] * s[c];
  sq += __shfl_xor(sq, 1, 64);
  sq += __shfl_xor(sq, 2, 64);          // norm over the 4-lane j-group
  float scale = (sq / (1.0f + sq)) / sqrtf(sq + 1e-8f);
  float* d = dst + (size_t)b * OUTD + tid * 8;
  f32x4 t0 = {scale*s[0], scale*s[1], scale*s[2], scale*s[3]};
  f32x4 t1 = {scale*s[4], scale*s[5], scale*s[6], scale*s[7]};
  *(f32x4*)d       = t0;
  *(f32x4*)(d + 4) = t1;
}

// ---------------------------------------------------------------------------
// route_fused: route phase with precomputed V + block-level s reduction.
// Grid 1024 = (b, g); block g covers i in [g*16, g*16+16), wave w -> 4 i's.
// R6-proven body: depth-2 prefetch, unpack-twice (short ps live ranges),
// no VGPR cap (spill avoidance).
// ---------------------------------------------------------------------------
__global__ __launch_bounds__(256) void route_fused(
    const unsigned short* __restrict__ P,     // [BS][ICAP][OUTD] bf16
    const float* __restrict__ Binit,          // [BS][JCAP][ICAP] f32
    float* __restrict__ B1,                   // [BS][ICAP][JCAP] f32
    const float* __restrict__ Vin,            // [BS][OUTD] f32 (j-major)
    float* __restrict__ part_out,             // [BS][NPART][OUTD] f32
    const int pass)
{
  __shared__ float Ps[4][2112];    // per-wave s partials [j*33+d]

  const int tid = threadIdx.x;
  const int l   = tid & 63;              // j
  const int w   = tid >> 6;
  const int b   = blockIdx.x >> 4;
  const int g   = blockIdx.x & 15;

  float vv[32];
  {
    const float* vp = Vin + (size_t)b * OUTD + l * D2;
    for (int q = 0; q < 8; ++q) {
      f32x4 t = *(const f32x4*)(vp + q * 4);
      vv[q*4+0] = t.x; vv[q*4+1] = t.y; vv[q*4+2] = t.z; vv[q*4+3] = t.w;
    }
  }

  const int i0 = g * 16 + w * 4;
  float bold[4];
  if (pass == 1) {
    f32x4 t = *(const f32x4*)(Binit + (size_t)(b * JCAP + l) * ICAP + i0);
    bold[0] = t.x; bold[1] = t.y; bold[2] = t.z; bold[3] = t.w;
  } else {
    for (int ii = 0; ii < 4; ++ii)
      bold[ii] = B1[((size_t)(b * ICAP + i0 + ii)) * JCAP + l];
  }

  float sacc[32];
  for (int k = 0; k < 32; ++k) sacc[k] = 0.f;

  const unsigned short* pbase = P + ((size_t)(b * ICAP + i0) * OUTD) + l * D2;
  uint4 ubuf[2][4];
  for (int q = 0; q < 4; ++q) ubuf[0][q] = *(const uint4*)(pbase + q * 8);
  for (int q = 0; q < 4; ++q) ubuf[1][q] = *(const uint4*)(pbase + OUTD + q * 8);

#pragma unroll
  for (int ii = 0; ii < 4; ++ii) {
    uint4 cur[4];
    for (int q = 0; q < 4; ++q) cur[q] = ubuf[ii & 1][q];
    if (ii + 2 < 4)
      for (int q = 0; q < 4; ++q)
        ubuf[ii & 1][q] = *(const uint4*)(pbase + (size_t)(ii + 2) * OUTD + q * 8);

    float db = 0.f;
    for (int q = 0; q < 4; ++q) {
      float ps[8]; unpack8(cur[q], ps);
      for (int k = 0; k < 8; ++k) db += ps[k] * vv[q * 8 + k];
    }
    float bnew = bold[ii] + db;
    if (pass == 1) B1[((size_t)(b * ICAP + i0 + ii)) * JCAP + l] = bnew;

    // softmax over 64 lanes (= J)
    float mx = bnew;
    for (int off = 1; off < 64; off <<= 1) mx = fmaxf(mx, __shfl_xor(mx, off, 64));
    float e = __expf(bnew - mx);
    float se = e;
    for (int off = 1; off < 64; off <<= 1) se += __shfl_xor(se, off, 64);
    float c = e / se;
    for (int q = 0; q < 4; ++q) {
      float ps[8]; unpack8(cur[q], ps);
      for (int k = 0; k < 8; ++k) sacc[q * 8 + k] += c * ps[k];
    }
  }

  for (int k = 0; k < 32; ++k) Ps[w][l * 33 + k] = sacc[k];
  __syncthreads();

  // block reduce 4 waves -> part_out[b][g]
  {
    const int o0 = tid * 8;
    float s[8];
    for (int c = 0; c < 8; ++c) {
      const int o = o0 + c, j = o >> 5, d = o & 31, idx = j * 33 + d;
      s[c] = Ps[0][idx] + Ps[1][idx] + Ps[2][idx] + Ps[3][idx];
    }
    float* dst = part_out + ((size_t)(b * NPART + g)) * OUTD + o0;
    f32x4 t0 = {s[0], s[1], s[2], s[3]};
    f32x4 t1 = {s[4], s[5], s[6], s[7]};
    *(f32x4*)dst       = t0;
    *(f32x4*)(dst + 4) = t1;
  }
}

// ---------------------------------------------------------------------------
extern "C" void kernel_launch(void* const* d_in, const int* in_sizes, int n_in,
                              void* d_out, int out_size, void* d_ws, size_t ws_size,
                              hipStream_t stream) {
  const float* x  = (const float*)d_in[0];
  const float* bi = (const float*)d_in[1];
  const float* W  = (const float*)d_in[2];
  const float* Wb = (const float*)d_in[3];
  float* out = (float*)d_out;

  char* ws = (char*)d_ws;
  const size_t MiB = 1024 * 1024;
  unsigned short* P        = (unsigned short*)ws;               // [0,64) MiB
  // overlays (lifetimes):
  //   xT [64,72): prep->gemm.  partial1 [64,72): route1->squash_v (after xT dead)
  //   s0part [72,76), Wbf [76,77), c0 [77,79): prep/gemm era
  //   partial2 [72,80): route2->squash_v (after s0part/Wbf/c0 dead)
  unsigned short* xT       = (unsigned short*)(ws + 64 * MiB);
  float*          partial1 = (float*)(ws + 64 * MiB);
  float*          s0part   = (float*)(ws + 72 * MiB);
  unsigned short* Wbf      = (unsigned short*)(ws + 76 * MiB);
  unsigned short* c0       = (unsigned short*)(ws + 77 * MiB);
  float*          partial2 = (float*)(ws + 72 * MiB);
  float* B1                = (float*)(ws + 80 * MiB);           // [80,84)
  float* V1                = (float*)(ws + 84 * MiB);           // 0.5 MiB
  float* V2                = (float*)(ws + 84 * MiB + 512 * 1024);

  prep<<<dim3(1536), 256, 0, stream>>>(W, x, bi, Wbf, xT, c0);
  gemm_pred<<<dim3(16, 2, 64), 256, 0, stream>>>(Wbf, xT, Wb, c0, P, s0part);
  squash_v<<<dim3(64), 256, 0, stream>>>(s0part, 8, V1);
  route_fused<<<dim3(1024), 256, 0, stream>>>(P, bi, B1, V1, partial1, 1);
  squash_v<<<dim3(64), 256, 0, stream>>>(partial1, NPART, V2);
  route_fused<<<dim3(1024), 256, 0, stream>>>(P, bi, B1, V2, partial2, 2);
  squash_v<<<dim3(64), 256, 0, stream>>>(partial2, NPART, out);
}